// Round 3
// baseline (460.890 us; speedup 1.0000x reference)
//
#include <hip/hip_runtime.h>
#include <cstdint>
#include <cstddef>

#define HEADS 4
#define HID 16
#define HD 64          // HEADS*HID
#define NCLS 10
#define NGRAPH 128
#define NEG_SLOPE 0.2f
#define SM_EPS 1e-16f

static inline size_t alignup(size_t x) { return (x + 255) & ~size_t(255); }

// ---------------- CSR build ----------------

__global__ void count_kernel(const int* __restrict__ dstA, int E, int Etot,
                             int* __restrict__ counts) {
    int e = blockIdx.x * blockDim.x + threadIdx.x;
    if (e >= Etot) return;
    int d = (e < E) ? dstA[e] : (e - E);
    atomicAdd(&counts[d], 1);
}

__global__ void scan1_kernel(const int* __restrict__ counts, int N, int* __restrict__ bsums) {
    __shared__ int sd[256];
    int tid = threadIdx.x;
    int i = blockIdx.x * 256 + tid;
    sd[tid] = (i < N) ? counts[i] : 0;
    __syncthreads();
    for (int s = 128; s > 0; s >>= 1) {
        if (tid < s) sd[tid] += sd[tid + s];
        __syncthreads();
    }
    if (tid == 0) bsums[blockIdx.x] = sd[0];
}

// exclusive scan of bsums in place (nb <= 256)
__global__ void scan2_kernel(int* __restrict__ bsums, int nb) {
    __shared__ int sd[256];
    int tid = threadIdx.x;
    int v = (tid < nb) ? bsums[tid] : 0;
    sd[tid] = v;
    __syncthreads();
    for (int off = 1; off < 256; off <<= 1) {
        int t = (tid >= off) ? sd[tid - off] : 0;
        __syncthreads();
        sd[tid] += t;
        __syncthreads();
    }
    if (tid < nb) bsums[tid] = sd[tid] - v;
}

__global__ void scan3_kernel(const int* __restrict__ counts, const int* __restrict__ bsums,
                             int N, int* __restrict__ row_ptr, int* __restrict__ cursor) {
    __shared__ int sd[256];
    int tid = threadIdx.x;
    int i = blockIdx.x * 256 + tid;
    int v = (i < N) ? counts[i] : 0;
    sd[tid] = v;
    __syncthreads();
    for (int off = 1; off < 256; off <<= 1) {
        int t = (tid >= off) ? sd[tid - off] : 0;
        __syncthreads();
        sd[tid] += t;
        __syncthreads();
    }
    int ex = sd[tid] - v + bsums[blockIdx.x];
    if (i < N) { row_ptr[i] = ex; cursor[i] = ex; }
}

__global__ void scatter_kernel(const int* __restrict__ srcA, const int* __restrict__ dstA,
                               int E, int Etot, int* __restrict__ cursor,
                               int* __restrict__ csr_src) {
    int e = blockIdx.x * blockDim.x + threadIdx.x;
    if (e >= Etot) return;
    int s = (e < E) ? srcA[e] : (e - E);
    int d = (e < E) ? dstA[e] : (e - E);
    int pos = atomicAdd(&cursor[d], 1);
    csr_src[pos] = s;
}

// ---------------- per-layer kernels ----------------

// h = in @ W (W staged in LDS, read once per 8 nodes), fused attention coefs.
// One wave handles 8 nodes; lane = output col.
template <int K>
__global__ __launch_bounds__(256) void gemm_attn_kernel(
        const float* __restrict__ in, const float* __restrict__ W,
        const float* __restrict__ as_, const float* __restrict__ ad_,
        float* __restrict__ h, float* __restrict__ asrc,
        float* __restrict__ adst, int N) {
    __shared__ float Wl[K * HD];
    __shared__ float avl[HD], adl[HD];
    int tid = threadIdx.x;
    for (int i = tid; i < K * HD; i += 256) Wl[i] = W[i];
    if (tid < HD) { avl[tid] = as_[tid]; adl[tid] = ad_[tid]; }
    __syncthreads();

    int lane = tid & 63, wave = tid >> 6;
    int head = lane >> 4;
    int base = (blockIdx.x * 4 + wave) * 8;
    if (base >= N) return;
    int cnt = min(8, N - base);

    float acc[8] = {0.f, 0.f, 0.f, 0.f, 0.f, 0.f, 0.f, 0.f};

    if (cnt == 8) {
#pragma unroll 4
        for (int k4 = 0; k4 < K / 4; k4++) {
            float4 xv[8];
#pragma unroll
            for (int i = 0; i < 8; i++)
                xv[i] = *(const float4*)(in + (size_t)(base + i) * K + 4 * k4);
            float w0 = Wl[(4 * k4 + 0) * HD + lane];
            float w1 = Wl[(4 * k4 + 1) * HD + lane];
            float w2 = Wl[(4 * k4 + 2) * HD + lane];
            float w3 = Wl[(4 * k4 + 3) * HD + lane];
#pragma unroll
            for (int i = 0; i < 8; i++)
                acc[i] += xv[i].x * w0 + xv[i].y * w1 + xv[i].z * w2 + xv[i].w * w3;
        }
    } else {
        for (int i = 0; i < cnt; i++) {
            float a = 0.f;
            for (int k = 0; k < K; k++) a += in[(size_t)(base + i) * K + k] * Wl[k * HD + lane];
            acc[i] = a;
        }
    }

#pragma unroll
    for (int i = 0; i < 8; i++) {
        if (i >= cnt) break;
        h[(size_t)(base + i) * HD + lane] = acc[i];
        float s = acc[i] * avl[lane];
        float d = acc[i] * adl[lane];
#pragma unroll
        for (int off = 1; off < 16; off <<= 1) {
            s += __shfl_xor(s, off);
            d += __shfl_xor(d, off);
        }
        if ((lane & 15) == 0) {
            asrc[(base + i) * HEADS + head] = s;
            adst[(base + i) * HEADS + head] = d;
        }
    }
}

// One wave per destination node: online-softmax gather over in-edges,
// 2 independent edge streams for ILP. Fused bias + SiLU epilogue.
__global__ void gat_gather_kernel(const int* __restrict__ row_ptr, const int* __restrict__ csr_src,
                                  int N, int Etot, const float* __restrict__ h,
                                  const float* __restrict__ asrc, const float* __restrict__ adst,
                                  const float* __restrict__ bias, float* __restrict__ out) {
    int wid = (int)((blockIdx.x * (long long)blockDim.x + threadIdx.x) >> 6);
    if (wid >= N) return;
    int lane = threadIdx.x & 63;
    int head = lane >> 4;
    int beg = row_ptr[wid];
    int end = (wid + 1 < N) ? row_ptr[wid + 1] : Etot;
    float ad = adst[wid * HEADS + head];

    float m0 = -3.0e38f, s0 = 0.f, a0 = 0.f;
    float m1 = -3.0e38f, s1 = 0.f, a1 = 0.f;
    int p = beg;
    for (; p + 1 < end; p += 2) {
        int e0 = csr_src[p];
        int e1 = csr_src[p + 1];
        float l0 = asrc[e0 * HEADS + head] + ad;
        float l1 = asrc[e1 * HEADS + head] + ad;
        l0 = (l0 > 0.f) ? l0 : NEG_SLOPE * l0;
        l1 = (l1 > 0.f) ? l1 : NEG_SLOPE * l1;
        float h0 = h[(size_t)e0 * HD + lane];
        float h1 = h[(size_t)e1 * HD + lane];
        float mn0 = fmaxf(m0, l0);
        float mn1 = fmaxf(m1, l1);
        float sc0 = __expf(m0 - mn0), w0 = __expf(l0 - mn0);
        float sc1 = __expf(m1 - mn1), w1 = __expf(l1 - mn1);
        s0 = s0 * sc0 + w0;  a0 = a0 * sc0 + w0 * h0;  m0 = mn0;
        s1 = s1 * sc1 + w1;  a1 = a1 * sc1 + w1 * h1;  m1 = mn1;
    }
    if (p < end) {
        int e0 = csr_src[p];
        float l0 = asrc[e0 * HEADS + head] + ad;
        l0 = (l0 > 0.f) ? l0 : NEG_SLOPE * l0;
        float h0 = h[(size_t)e0 * HD + lane];
        float mn0 = fmaxf(m0, l0);
        float sc0 = __expf(m0 - mn0), w0 = __expf(l0 - mn0);
        s0 = s0 * sc0 + w0;  a0 = a0 * sc0 + w0 * h0;  m0 = mn0;
    }
    // merge the two streams
    float mn = fmaxf(m0, m1);
    float sc0 = __expf(m0 - mn), sc1 = __expf(m1 - mn);
    float ssum = s0 * sc0 + s1 * sc1;
    float acc = a0 * sc0 + a1 * sc1;

    float v = acc / (ssum + SM_EPS) + bias[lane];
    out[(size_t)wid * HD + lane] = v / (1.f + expf(-v));
}

// Run-length pooled sum: one wave per 64 consecutive (batch-sorted) nodes.
__global__ void pool_kernel(const float* __restrict__ h, const int* __restrict__ batch,
                            float* __restrict__ pooled, int N) {
    int gw = (int)((blockIdx.x * (long long)blockDim.x + threadIdx.x) >> 6);
    int lane = threadIdx.x & 63;
    int n_begin = gw * 64;
    if (n_begin >= N) return;
    int n_end = min(n_begin + 64, N);
    float acc = 0.f;
    int g = batch[n_begin];
    for (int n = n_begin; n < n_end; n++) {
        int gn = batch[n];
        if (gn != g) {
            atomicAdd(&pooled[(size_t)g * HD + lane], acc);
            acc = 0.f;
            g = gn;
        }
        acc += h[(size_t)n * HD + lane];
    }
    atomicAdd(&pooled[(size_t)g * HD + lane], acc);
}

__global__ void head_kernel(const float* __restrict__ pooled, const float* __restrict__ Wr,
                            const float* __restrict__ br, float* __restrict__ out) {
    int g = threadIdx.x;
    if (g >= NGRAPH) return;
    float l[NCLS];
    float mx = -1e30f;
#pragma unroll
    for (int c = 0; c < NCLS; c++) {
        float a = br[c];
        for (int k = 0; k < HD; k++) a += pooled[(size_t)g * HD + k] * Wr[k * NCLS + c];
        a = (a > 0.f) ? a : 0.f;
        l[c] = a;
        mx = fmaxf(mx, a);
    }
    float se = 0.f;
#pragma unroll
    for (int c = 0; c < NCLS; c++) se += expf(l[c] - mx);
    float lse = logf(se);
#pragma unroll
    for (int c = 0; c < NCLS; c++) out[(size_t)g * NCLS + c] = l[c] - mx - lse;
}

extern "C" void kernel_launch(void* const* d_in, const int* in_sizes, int n_in,
                              void* d_out, int out_size, void* d_ws, size_t ws_size,
                              hipStream_t stream) {
    const float* x = (const float*)d_in[0];
    const int* ei = (const int*)d_in[1];
    const int* batch = (const int*)d_in[2];
    const float* W[3]  = {(const float*)d_in[3], (const float*)d_in[7],  (const float*)d_in[11]};
    const float* bb[3] = {(const float*)d_in[4], (const float*)d_in[8],  (const float*)d_in[12]};
    const float* as_[3] = {(const float*)d_in[5], (const float*)d_in[9], (const float*)d_in[13]};
    const float* ad_[3] = {(const float*)d_in[6], (const float*)d_in[10], (const float*)d_in[14]};
    const float* Wr = (const float*)d_in[15];
    const float* br = (const float*)d_in[16];

    const int N = in_sizes[2];          // 50000
    const int E = in_sizes[1] / 2;      // 800000
    const int Etot = E + N;             // + self loops
    // F0 = in_sizes[0] / N;            // 128 (compile-time template below)

    char* p = (char*)d_ws;
    float* hproj = (float*)p; p += alignup((size_t)N * HD * 4);
    float* hbuf  = (float*)p; p += alignup((size_t)N * HD * 4);
    float* asrc  = (float*)p; p += alignup((size_t)N * HEADS * 4);
    float* adst  = (float*)p; p += alignup((size_t)N * HEADS * 4);
    int* counts  = (int*)p;   p += alignup((size_t)N * 4);
    int* row_ptr = (int*)p;   p += alignup((size_t)N * 4);
    int* cursor  = (int*)p;   p += alignup((size_t)N * 4);
    int* bsums   = (int*)p;   p += alignup(256 * 4);
    int* csr_src = (int*)p;   p += alignup((size_t)Etot * 4);
    float* pooled = (float*)p; p += alignup((size_t)NGRAPH * HD * 4);

    const int* srcA = ei;
    const int* dstA = ei + E;

    // ---- CSR build (once, reused by all 3 layers) ----
    hipMemsetAsync(counts, 0, (size_t)N * 4, stream);
    count_kernel<<<(Etot + 255) / 256, 256, 0, stream>>>(dstA, E, Etot, counts);
    int nb = (N + 255) / 256;
    scan1_kernel<<<nb, 256, 0, stream>>>(counts, N, bsums);
    scan2_kernel<<<1, 256, 0, stream>>>(bsums, nb);
    scan3_kernel<<<nb, 256, 0, stream>>>(counts, bsums, N, row_ptr, cursor);
    scatter_kernel<<<(Etot + 255) / 256, 256, 0, stream>>>(srcA, dstA, E, Etot, cursor, csr_src);

    // ---- layers ----
    int gather_blocks = (int)(((long long)N * 64 + 255) / 256);
    int gemm_blocks = (N + 31) / 32;   // 4 waves/block * 8 nodes/wave
    for (int layer = 0; layer < 3; layer++) {
        const float* in = (layer == 0) ? x : hbuf;
        if (layer == 0)
            gemm_attn_kernel<128><<<gemm_blocks, 256, 0, stream>>>(in, W[layer], as_[layer],
                                                                   ad_[layer], hproj, asrc, adst, N);
        else
            gemm_attn_kernel<64><<<gemm_blocks, 256, 0, stream>>>(in, W[layer], as_[layer],
                                                                  ad_[layer], hproj, asrc, adst, N);
        gat_gather_kernel<<<gather_blocks, 256, 0, stream>>>(row_ptr, csr_src, N, Etot, hproj,
                                                             asrc, adst, bb[layer], hbuf);
    }

    // ---- pooling + head ----
    hipMemsetAsync(pooled, 0, (size_t)NGRAPH * HD * 4, stream);
    int pool_waves = (N + 63) / 64;
    pool_kernel<<<(pool_waves * 64 + 255) / 256, 256, 0, stream>>>(hbuf, batch, pooled, N);
    head_kernel<<<1, 128, 0, stream>>>(pooled, Wr, br, (float*)d_out);
}